// Round 6
// baseline (164.837 us; speedup 1.0000x reference)
//
#include <hip/hip_runtime.h>

typedef unsigned short u16;
typedef __attribute__((ext_vector_type(8))) __bf16 bf16x8;
typedef __attribute__((ext_vector_type(4))) float f32x4;

struct alignas(8) U16x4 { u16 x, y, z, w; };

#define MFMA16(a, b, c) __builtin_amdgcn_mfma_f32_16x16x32_bf16(a, b, c, 0, 0, 0)

__device__ __forceinline__ u16 f2bf(float f) {
    union { float f; unsigned u; } v; v.f = f;
    unsigned r = v.u + 0x7fffu + ((v.u >> 16) & 1u);
    return (u16)(r >> 16);
}

__device__ __forceinline__ unsigned cvt_pk_bf16(float lo, float hi) {
    unsigned r;
    asm("v_cvt_pk_bf16_f32 %0, %1, %2" : "=v"(r) : "v"(lo), "v"(hi));
    return r;
}

__device__ __forceinline__ float fexp2(float x) {   // raw v_exp_f32 (2^x)
    float r;
    asm("v_exp_f32 %0, %1" : "=v"(r) : "v"(x));
    return r;
}

__device__ __forceinline__ void gload_lds16(const void* g, void* l) {
    __builtin_amdgcn_global_load_lds(
        (__attribute__((address_space(1))) void*)g,
        (__attribute__((address_space(3))) void*)l, 16, 0, 0);
}

// ---------------------------------------------------------------------------
// prep: fused LN(query)+LN(context)+weight-conversion (unchanged from R5).
// ---------------------------------------------------------------------------
__global__ __launch_bounds__(256)
void prep(const float* __restrict__ query, const float* __restrict__ context,
          const float* __restrict__ g_q, const float* __restrict__ b_q,
          const float* __restrict__ g_kv, const float* __restrict__ b_kv,
          float* __restrict__ qn32, u16* __restrict__ qnb, u16* __restrict__ cnb,
          const float4* __restrict__ w0, const float4* __restrict__ w1,
          const float4* __restrict__ w2, const float4* __restrict__ w3,
          U16x4* __restrict__ o0, U16x4* __restrict__ o1,
          U16x4* __restrict__ o2, U16x4* __restrict__ o3)
{
    const int blk = blockIdx.x;
    if (blk < 2560) {
        const float *x, *g, *be; float* y32; u16* y16; int rb;
        if (blk < 512) { x = query;   g = g_q;  be = b_q;  y32 = qn32;    y16 = qnb; rb = blk; }
        else           { x = context; g = g_kv; be = b_kv; y32 = nullptr; y16 = cnb; rb = blk - 512; }
        const int wid = threadIdx.x >> 6, lane = threadIdx.x & 63;
        const size_t row = (size_t)rb * 4 + wid;
        const float4* xr = (const float4*)(x + row * 1024);
        float4 v[4];
        float s = 0.f, ss = 0.f;
#pragma unroll
        for (int i = 0; i < 4; ++i) {
            v[i] = xr[i * 64 + lane];
            s  += (v[i].x + v[i].y) + (v[i].z + v[i].w);
            ss += (v[i].x * v[i].x + v[i].y * v[i].y) + (v[i].z * v[i].z + v[i].w * v[i].w);
        }
#pragma unroll
        for (int o = 32; o; o >>= 1) { s += __shfl_xor(s, o, 64); ss += __shfl_xor(ss, o, 64); }
        const float mu = s * (1.f / 1024.f);
        const float rstd = rsqrtf(ss * (1.f / 1024.f) - mu * mu + 1e-5f);
#pragma unroll
        for (int i = 0; i < 4; ++i) {
            float4 gv = ((const float4*)g)[i * 64 + lane];
            float4 bv = ((const float4*)be)[i * 64 + lane];
            float4 o;
            o.x = (v[i].x - mu) * rstd * gv.x + bv.x;
            o.y = (v[i].y - mu) * rstd * gv.y + bv.y;
            o.z = (v[i].z - mu) * rstd * gv.z + bv.z;
            o.w = (v[i].w - mu) * rstd * gv.w + bv.w;
            if (y32) ((float4*)(y32 + row * 1024))[i * 64 + lane] = o;
            U16x4 pk = { f2bf(o.x), f2bf(o.y), f2bf(o.z), f2bf(o.w) };
            ((U16x4*)(y16 + row * 1024))[i * 64 + lane] = pk;
        }
    } else {
        const int i = (blk - 2560) * 256 + threadIdx.x;
        float4 v;
        v = w0[i]; o0[i] = { f2bf(v.x), f2bf(v.y), f2bf(v.z), f2bf(v.w) };
        v = w1[i]; o1[i] = { f2bf(v.x), f2bf(v.y), f2bf(v.z), f2bf(v.w) };
        v = w2[i]; o2[i] = { f2bf(v.x), f2bf(v.y), f2bf(v.z), f2bf(v.w) };
        v = w3[i]; o3[i] = { f2bf(v.x), f2bf(v.y), f2bf(v.z), f2bf(v.w) };
    }
}

// ---------------------------------------------------------------------------
// Merged K+V projection GEMM (unchanged from R4/R5).
// ---------------------------------------------------------------------------
__global__ __launch_bounds__(512, 4)
void gemm_kv(const u16* __restrict__ A, const u16* __restrict__ Wk,
             const u16* __restrict__ Wv, const float* __restrict__ bkp,
             const float* __restrict__ bvp, u16* __restrict__ Kout,
             u16* __restrict__ Vt)
{
    constexpr int K = 1024, N = 1024, BK = 64;
    __shared__ __align__(16) u16 sA[128 * BK];
    __shared__ __align__(16) u16 sK[128 * BK];
    __shared__ __align__(16) u16 sV[128 * BK];
    const int tid = threadIdx.x, wid = tid >> 6, lane = tid & 63;
    const int lr = lane & 15, lg = lane >> 4;
    const int wr = wid >> 2, wc = wid & 3;
    const int row0 = blockIdx.x * 128, col0 = blockIdx.y * 128;
    const int srow = wid * 8 + (lane >> 3), scol = (lane & 7) * 8;

    const u16* Ag = A  + (size_t)(row0 + srow) * K + scol;
    const u16* Kg = Wk + (size_t)(col0 + srow) * K + scol;
    const u16* Vg = Wv + (size_t)(col0 + srow) * K + scol;

    f32x4 ka[4][2], va[4][2];
#pragma unroll
    for (int m = 0; m < 4; ++m)
#pragma unroll
        for (int n = 0; n < 2; ++n) {
            ka[m][n] = (f32x4){0.f, 0.f, 0.f, 0.f};
            va[m][n] = (f32x4){0.f, 0.f, 0.f, 0.f};
        }

    for (int k0 = 0; k0 < K; k0 += BK) {
        __syncthreads();
#pragma unroll
        for (int i = 0; i < 2; ++i) {
            gload_lds16(Ag + (size_t)i * 64 * K + k0, (char*)sA + i * 8192 + wid * 1024);
            gload_lds16(Kg + (size_t)i * 64 * K + k0, (char*)sK + i * 8192 + wid * 1024);
            gload_lds16(Vg + (size_t)i * 64 * K + k0, (char*)sV + i * 8192 + wid * 1024);
        }
        __syncthreads();
#pragma unroll
        for (int kk = 0; kk < 2; ++kk) {
            bf16x8 af[4], bk[2], bv[2];
#pragma unroll
            for (int m = 0; m < 4; ++m)
                af[m] = *(const bf16x8*)&sA[(wr * 64 + m * 16 + lr) * BK + kk * 32 + lg * 8];
#pragma unroll
            for (int n = 0; n < 2; ++n) {
                bk[n] = *(const bf16x8*)&sK[(wc * 32 + n * 16 + lr) * BK + kk * 32 + lg * 8];
                bv[n] = *(const bf16x8*)&sV[(wc * 32 + n * 16 + lr) * BK + kk * 32 + lg * 8];
            }
#pragma unroll
            for (int m = 0; m < 4; ++m)
#pragma unroll
                for (int n = 0; n < 2; ++n) {
                    ka[m][n] = MFMA16(af[m], bk[n], ka[m][n]);
                    va[m][n] = MFMA16(af[m], bv[n], va[m][n]);
                }
        }
    }

#pragma unroll
    for (int m = 0; m < 4; ++m) {
#pragma unroll
        for (int n = 0; n < 2; ++n) {
            const int r = row0 + wr * 64 + m * 16 + lg * 4;
            const int c = col0 + wc * 32 + n * 16 + lr;
            const float kb = bkp[c], vb = bvp[c];
#pragma unroll
            for (int j = 0; j < 4; ++j)
                Kout[(size_t)(r + j) * N + c] = f2bf(ka[m][n][j] + kb);
            const size_t base = ((size_t)(r >> 12) * 1024 + c) * 4096 + (r & 4095);
            U16x4 pk = { f2bf(va[m][n][0] + vb), f2bf(va[m][n][1] + vb),
                         f2bf(va[m][n][2] + vb), f2bf(va[m][n][3] + vb) };
            *(U16x4*)&Vt[base] = pk;
        }
    }
}

// ---------------------------------------------------------------------------
// Q/O projection GEMM, 64x128 tile (unchanged from R4/R5).
// ---------------------------------------------------------------------------
template<int MODE>
__global__ __launch_bounds__(256)
void gemm_bt64(const u16* __restrict__ A, const u16* __restrict__ W,
               const float* __restrict__ bias, const float* __restrict__ resid,
               void* __restrict__ Cp, int M, int N, int K, float alpha)
{
    constexpr int BK = 64;
    __shared__ __align__(16) u16 sA[64 * BK];
    __shared__ __align__(16) u16 sB[128 * BK];
    const int tid = threadIdx.x, wid = tid >> 6, lane = tid & 63;
    const int lr = lane & 15, lg = lane >> 4;
    const int wr = wid >> 1, wc = wid & 1;
    const int row0 = blockIdx.x * 64, col0 = blockIdx.y * 128;
    const int srow = wid * 8 + (lane >> 3), scol = (lane & 7) * 8;

    const u16* Ag = A + (size_t)(row0 + srow) * K + scol;
    const u16* Wg = W + (size_t)(col0 + srow) * K + scol;

    f32x4 acc[2][4];
#pragma unroll
    for (int m = 0; m < 2; ++m)
#pragma unroll
        for (int n = 0; n < 4; ++n) acc[m][n] = (f32x4){0.f, 0.f, 0.f, 0.f};

    for (int k0 = 0; k0 < K; k0 += BK) {
        __syncthreads();
#pragma unroll
        for (int i = 0; i < 2; ++i)
            gload_lds16(Ag + (size_t)i * 32 * K + k0, (char*)sA + i * 4096 + wid * 1024);
#pragma unroll
        for (int i = 0; i < 4; ++i)
            gload_lds16(Wg + (size_t)i * 32 * K + k0, (char*)sB + i * 4096 + wid * 1024);
        __syncthreads();
#pragma unroll
        for (int kk = 0; kk < 2; ++kk) {
            bf16x8 af[2], bfr[4];
#pragma unroll
            for (int m = 0; m < 2; ++m)
                af[m] = *(const bf16x8*)&sA[(wr * 32 + m * 16 + lr) * BK + kk * 32 + lg * 8];
#pragma unroll
            for (int n = 0; n < 4; ++n)
                bfr[n] = *(const bf16x8*)&sB[(wc * 64 + n * 16 + lr) * BK + kk * 32 + lg * 8];
#pragma unroll
            for (int m = 0; m < 2; ++m)
#pragma unroll
                for (int n = 0; n < 4; ++n)
                    acc[m][n] = MFMA16(af[m], bfr[n], acc[m][n]);
        }
    }

#pragma unroll
    for (int m = 0; m < 2; ++m) {
#pragma unroll
        for (int n = 0; n < 4; ++n) {
            const int r = row0 + wr * 32 + m * 16 + lg * 4;
            const int c = col0 + wc * 64 + n * 16 + lr;
            const float bv = bias[c];
            if constexpr (MODE == 0) {
                u16* C = (u16*)Cp;
#pragma unroll
                for (int j = 0; j < 4; ++j)
                    C[(size_t)(r + j) * N + c] = f2bf((acc[m][n][j] + bv) * alpha);
            } else {
                float* C = (float*)Cp;
#pragma unroll
                for (int j = 0; j < 4; ++j)
                    C[(size_t)(r + j) * N + c] =
                        (acc[m][n][j] + bv) * alpha + resid[(size_t)(r + j) * N + c];
            }
        }
    }
}

// ---------------------------------------------------------------------------
// Flash cross-attention, v5: LDS-traffic-minimized.
//   Diagnosis: v3/v4 were LDS-BW-bound (~10.2 MB LDS reads per CU ~= 75% of
//   runtime at 85 B/cyc). Fix: each wave owns 32 q-rows (2 MFMA col-blocks)
//   so only 2 waves share each K/V tile -> K/V LDS read traffic halves
//   (160KB -> 96KB per block-iter). Block = 256 thr / 4 waves:
//   grp = wid>>1 (kv half), w = wid&1 (q 32-block). R3-style loop retained:
//   stage(t+1) -> compute(t) -> vmcnt(0)+barrier. LDS 80KB -> 2 blocks/CU.
// ---------------------------------------------------------------------------
__global__ __launch_bounds__(256, 2)
void attn_fwd(const u16* __restrict__ Q, const u16* __restrict__ Kg,
              const u16* __restrict__ Vt, u16* __restrict__ O)
{
    constexpr int D = 1024, CSTR = 36;
    __shared__ __align__(16) char smem[81920];   // K 32K | V 32K | P 16K

    const int tid = threadIdx.x, wid = tid >> 6, lane = tid & 63;
    const int grp = wid >> 1, w = wid & 1;
    const int lr = lane & 15, lg = lane >> 4;
    const int rs = lr & 7;
    const int pkey = (lr & 7) << 4;

    // XCD swizzle: 512 wgs, 64 consecutive work items per XCD
    const int fid = blockIdx.x;
    const int wkid = (fid & 7) * 64 + (fid >> 3);
    const int qblk = wkid & 15, h = (wkid >> 4) & 15, b = wkid >> 8;
    const int q0 = qblk * 64 + w * 32;

    // Q fragments for 2 q col-blocks (Q pre-scaled by 0.125*log2e)
    const u16* Qbase = Q + (size_t)(b * 1024 + q0 + lr) * D + h * 64;
    bf16x8 qf[2][2];
    qf[0][0] = *(const bf16x8*)(Qbase + lg * 8);
    qf[0][1] = *(const bf16x8*)(Qbase + 32 + lg * 8);
    qf[1][0] = *(const bf16x8*)(Qbase + (size_t)16 * D + lg * 8);
    qf[1][1] = *(const bf16x8*)(Qbase + (size_t)16 * D + 32 + lg * 8);

    // staging: wave stages rows w*32 + i*8 + (lane>>3), i=0..3, of its
    // group's 64-row K tile (and d-rows of the V^T tile). scol swizzled.
    const int srow0 = lane >> 3;
    const int scol = ((lane & 7) ^ srow0) * 8;
    const u16* kp = Kg + (size_t)(b * 4096 + grp * 2048 + w * 32 + srow0) * D + h * 64 + scol;
    const u16* vp = Vt + ((size_t)(b * 16 + h) * 64 + w * 32 + srow0) * 4096 + grp * 2048 + scol;

    char* sPw = smem + 65536 + wid * 4096;   // per-wave 32x128B P strip

    f32x4 po[4][2];
#pragma unroll
    for (int df = 0; df < 4; ++df) {
        po[df][0] = (f32x4){0.f, 0.f, 0.f, 0.f};
        po[df][1] = (f32x4){0.f, 0.f, 0.f, 0.f};
    }
    float m0 = -INFINITY, m1 = -INFINITY, l0 = 0.f, l1 = 0.f;

    auto stage = [&](int buf, int kv0) {
        char* kd = smem + buf * 16384 + grp * 8192 + w * 4096;
        char* vd = smem + 32768 + buf * 16384 + grp * 8192 + w * 4096;
#pragma unroll
        for (int i = 0; i < 4; ++i) {
            gload_lds16(kp + (size_t)(kv0 + i * 8) * D,     kd + i * 1024);
            gload_lds16(vp + (size_t)(i * 8) * 4096 + kv0,  vd + i * 1024);
        }
    };

    stage(0, 0);
    asm volatile("s_waitcnt vmcnt(0)" ::: "memory");
    asm volatile("s_barrier" ::: "memory");

    for (int t = 0; t < 32; ++t) {
        const int cur = t & 1;
        if (t < 31) stage(cur ^ 1, (t + 1) * 64);

        const u16* kb = (const u16*)(smem + cur * 16384 + grp * 8192);
        const u16* vb = (const u16*)(smem + 32768 + cur * 16384 + grp * 8192);

        // S^T[kv][q] = K . Q^T for both q col-blocks (log2 domain)
        f32x4 s4[4][2];
#pragma unroll
        for (int f = 0; f < 4; ++f) {
            const int r = f * 16 + lr;
            bf16x8 k0v = *(const bf16x8*)&kb[r * 64 + (lg ^ rs) * 8];
            bf16x8 k1v = *(const bf16x8*)&kb[r * 64 + ((lg + 4) ^ rs) * 8];
#pragma unroll
            for (int qc = 0; qc < 2; ++qc) {
                f32x4 z = (f32x4){0.f, 0.f, 0.f, 0.f};
                z = MFMA16(k0v, qf[qc][0], z);
                s4[f][qc] = MFMA16(k1v, qf[qc][1], z);
            }
        }

        // defer-max online softmax (base-2), independent per q col-block
        float pm0 = s4[0][0][0], pm1 = s4[0][1][0];
#pragma unroll
        for (int f = 0; f < 4; ++f) {
            pm0 = fmaxf(pm0, fmaxf(fmaxf(s4[f][0][0], s4[f][0][1]), fmaxf(s4[f][0][2], s4[f][0][3])));
            pm1 = fmaxf(pm1, fmaxf(fmaxf(s4[f][1][0], s4[f][1][1]), fmaxf(s4[f][1][2], s4[f][1][3])));
        }
        if (!__all(pm0 <= m0 && pm1 <= m1)) {
            float t0 = fmaxf(pm0, __shfl_xor(pm0, 16, 64));
            t0 = fmaxf(t0, __shfl_xor(t0, 32, 64));
            float t1 = fmaxf(pm1, __shfl_xor(pm1, 16, 64));
            t1 = fmaxf(t1, __shfl_xor(t1, 32, 64));
            const float mn0 = fmaxf(m0, t0), mn1 = fmaxf(m1, t1);
            const float c0 = fexp2(m0 - mn0), c1 = fexp2(m1 - mn1);
            l0 *= c0; l1 *= c1;
#pragma unroll
            for (int df = 0; df < 4; ++df) { po[df][0] *= c0; po[df][1] *= c1; }
            m0 = mn0; m1 = mn1;
        }
        float ls0 = 0.f, ls1 = 0.f;
        uint2 pk[4][2];
#pragma unroll
        for (int f = 0; f < 4; ++f) {
            float a0 = fexp2(s4[f][0][0] - m0), a1 = fexp2(s4[f][0][1] - m0);
            float a2 = fexp2(s4[f][0][2] - m0), a3 = fexp2(s4[f][0][3] - m0);
            ls0 += (a0 + a1) + (a2 + a3);
            pk[f][0].x = cvt_pk_bf16(a0, a1);
            pk[f][0].y = cvt_pk_bf16(a2, a3);
            float b0 = fexp2(s4[f][1][0] - m1), b1 = fexp2(s4[f][1][1] - m1);
            float b2 = fexp2(s4[f][1][2] - m1), b3 = fexp2(s4[f][1][3] - m1);
            ls1 += (b0 + b1) + (b2 + b3);
            pk[f][1].x = cvt_pk_bf16(b0, b1);
            pk[f][1].y = cvt_pk_bf16(b2, b3);
        }
        l0 += ls0; l1 += ls1;

        // P -> wave-private strip (rows q: [0,16) qc0, [16,32) qc1)
#pragma unroll
        for (int f = 0; f < 4; ++f) {
            *(uint2*)(sPw + lr * 128        + ((f * 32 + lg * 8) ^ pkey)) = pk[f][0];
            *(uint2*)(sPw + (16 + lr) * 128 + ((f * 32 + lg * 8) ^ pkey)) = pk[f][1];
        }

        // out^T[d][q] += V^T . P^T   (vf shared by both q col-blocks)
#pragma unroll
        for (int c = 0; c < 2; ++c) {
            bf16x8 pf0 = *(const bf16x8*)(sPw + lr * 128        + ((c * 64 + lg * 16) ^ pkey));
            bf16x8 pf1 = *(const bf16x8*)(sPw + (16 + lr) * 128 + ((c * 64 + lg * 16) ^ pkey));
#pragma unroll
            for (int df = 0; df < 4; ++df) {
                const int r = df * 16 + lr;
                bf16x8 vf = *(const bf16x8*)&vb[r * 64 + ((c * 4 + lg) ^ rs) * 8];
                po[df][0] = MFMA16(vf, pf0, po[df][0]);
                po[df][1] = MFMA16(vf, pf1, po[df][1]);
            }
        }

        asm volatile("s_waitcnt vmcnt(0)" ::: "memory");
        asm volatile("s_barrier" ::: "memory");
    }

    // reduce per-lane l across the q-column
    l0 += __shfl_xor(l0, 16, 64); l0 += __shfl_xor(l0, 32, 64);
    l1 += __shfl_xor(l1, 16, 64); l1 += __shfl_xor(l1, 32, 64);

    // merge the two kv halves through LDS (K region is dead now)
    float* cb = (float*)smem;
    if (grp == 1) {
        float* dst = cb + (size_t)(w * 64 + lane) * CSTR;
        dst[0] = m0; dst[1] = m1; dst[2] = l0; dst[3] = l1;
#pragma unroll
        for (int df = 0; df < 4; ++df)
#pragma unroll
            for (int qc = 0; qc < 2; ++qc)
#pragma unroll
                for (int j = 0; j < 4; ++j)
                    dst[4 + (df * 2 + qc) * 4 + j] = po[df][qc][j];
    }
    __syncthreads();
    if (grp == 0) {
        const float* src = cb + (size_t)(w * 64 + lane) * CSTR;
        const float sm0 = src[0], sm1 = src[1], sl0 = src[2], sl1 = src[3];
        const float M0 = fmaxf(m0, sm0), M1 = fmaxf(m1, sm1);
        const float a0 = fexp2(m0 - M0), b0 = fexp2(sm0 - M0);
        const float a1 = fexp2(m1 - M1), b1 = fexp2(sm1 - M1);
        const float rl0 = 1.f / (l0 * a0 + sl0 * b0);
        const float rl1 = 1.f / (l1 * a1 + sl1 * b1);
        u16* Orow = O + (size_t)(b * 1024 + q0 + lr) * D + h * 64;
#pragma unroll
        for (int qc = 0; qc < 2; ++qc) {
            const float ca = qc ? a1 : a0, cbb = qc ? b1 : b0, rl = qc ? rl1 : rl0;
            u16* orow = Orow + (size_t)qc * 16 * D;
#pragma unroll
            for (int df = 0; df < 4; ++df) {
                const float* sv = src + 4 + (df * 2 + qc) * 4;
                U16x4 opk = { f2bf((po[df][qc][0] * ca + sv[0] * cbb) * rl),
                              f2bf((po[df][qc][1] * ca + sv[1] * cbb) * rl),
                              f2bf((po[df][qc][2] * ca + sv[2] * cbb) * rl),
                              f2bf((po[df][qc][3] * ca + sv[3] * cbb) * rl) };
                *(U16x4*)&orow[df * 16 + lg * 4] = opk;
            }
        }
    }
}

// ---------------------------------------------------------------------------
extern "C" void kernel_launch(void* const* d_in, const int* in_sizes, int n_in,
                              void* d_out, int out_size, void* d_ws, size_t ws_size,
                              hipStream_t stream)
{
    const float* query   = (const float*)d_in[0];
    const float* context = (const float*)d_in[1];
    const float* wq = (const float*)d_in[2];
    const float* bq = (const float*)d_in[3];
    const float* wk = (const float*)d_in[4];
    const float* bk = (const float*)d_in[5];
    const float* wv = (const float*)d_in[6];
    const float* bv = (const float*)d_in[7];
    const float* wo = (const float*)d_in[8];
    const float* bo = (const float*)d_in[9];
    const float* g_q  = (const float*)d_in[10];
    const float* b_q  = (const float*)d_in[11];
    const float* g_kv = (const float*)d_in[12];
    const float* b_kv = (const float*)d_in[13];

    char* p = (char*)d_ws;
    auto alloc = [&](size_t bytes) { char* r = p; p += (bytes + 255) & ~(size_t)255; return r; };
    u16*   wqb  = (u16*)alloc(1024 * 1024 * 2);
    u16*   wkb  = (u16*)alloc(1024 * 1024 * 2);
    u16*   wvb  = (u16*)alloc(1024 * 1024 * 2);
    u16*   wob  = (u16*)alloc(1024 * 1024 * 2);
    float* qn32 = (float*)alloc((size_t)2048 * 1024 * 4);
    u16*   qnb  = (u16*)alloc((size_t)2048 * 1024 * 2);
    u16*   cnb  = (u16*)alloc((size_t)8192 * 1024 * 2);
    u16*   Qb   = (u16*)alloc((size_t)2048 * 1024 * 2);
    u16*   Kb   = (u16*)alloc((size_t)8192 * 1024 * 2);
    u16*   Vtb  = (u16*)alloc((size_t)8192 * 1024 * 2);
    u16*   AOb  = (u16*)alloc((size_t)2048 * 1024 * 2);

    prep<<<3584, 256, 0, stream>>>(query, context, g_q, b_q, g_kv, b_kv,
                                   qn32, qnb, cnb,
                                   (const float4*)wq, (const float4*)wk,
                                   (const float4*)wv, (const float4*)wo,
                                   (U16x4*)wqb, (U16x4*)wkb, (U16x4*)wvb, (U16x4*)wob);

    // Q = (qn.wq^T + bq) * 0.125 * log2(e)  (attn scale + exp2 conversion folded)
    gemm_bt64<0><<<dim3(32, 8), 256, 0, stream>>>(qnb, wqb, bq, nullptr, Qb, 2048, 1024, 1024, 0.18033688f);
    // K row-major + V transposed, one pass over cnb
    gemm_kv<<<dim3(64, 8), 512, 0, stream>>>(cnb, wkb, wvb, bk, bv, Kb, Vtb);

    attn_fwd<<<dim3(512), 256, 0, stream>>>(Qb, Kb, Vtb, AOb);

    // out = qn + AO.wo^T + bo   (f32 output, residual fused)
    gemm_bt64<1><<<dim3(32, 8), 256, 0, stream>>>(AOb, wob, bo, qn32, d_out, 2048, 1024, 1024, 1.0f);
}